// Round 10
// baseline (162.943 us; speedup 1.0000x reference)
//
#include <hip/hip_runtime.h>
#include <math.h>

#define BB 4
#define TT 4096
#define EE 1024
#define HH 64

typedef __attribute__((ext_vector_type(8))) short bf16x8;    // 8 bf16 = 4 VGPRs
typedef __attribute__((ext_vector_type(4))) float f32x4;
typedef __attribute__((ext_vector_type(16))) float f32x16;

#define MFMA16(a, b, c) __builtin_amdgcn_mfma_f32_16x16x32_bf16(a, b, c, 0, 0, 0)
#define MFMA32(a, b, c) __builtin_amdgcn_mfma_f32_32x32x16_bf16(a, b, c, 0, 0, 0)

__device__ __forceinline__ unsigned short f2bf_rne(float f) {
    unsigned u = __float_as_uint(f);
    unsigned r = u + 0x7fffu + ((u >> 16) & 1u);   // round-to-nearest-even
    return (unsigned short)(r >> 16);
}
__device__ __forceinline__ float bf2f(unsigned short h) {
    return __uint_as_float(((unsigned)h) << 16);
}

// async 16B global->LDS DMA; LDS dest = base + lane*16 (wave-uniform base)
__device__ __forceinline__ void async_copy16(const void* g, void* l) {
    __builtin_amdgcn_global_load_lds(
        (const __attribute__((address_space(1))) void*)g,
        (__attribute__((address_space(3))) void*)l, 16, 0, 0);
}
// wait until <= N vector-memory ops outstanding (lgkm/exp untouched);
// vmcnt is a 6-bit split field: [3:0] and [15:14]
template<int N>
__device__ __forceinline__ void wait_vm() {
    __builtin_amdgcn_s_waitcnt(0x0f70 | (N & 15) | ((N >> 4) << 14));
}

// ---------------------------------------------------------------------------
// Kernel 0: W prep via LDS transpose.  wt_hi/lo[h192][e] = split-bf16 of
// W{q|k|v}[e][h].  48 blocks.  (unchanged from R9)
// ---------------------------------------------------------------------------
__global__ __launch_bounds__(256) void wprep_kernel(
    const float* __restrict__ Wq, const float* __restrict__ Wk,
    const float* __restrict__ Wv,
    unsigned short* __restrict__ wt_hi, unsigned short* __restrict__ wt_lo)
{
    __shared__ float ts[64][65];
    const int which = blockIdx.x >> 4;
    const int e0 = (blockIdx.x & 15) * 64;
    const float* W = (which == 0) ? Wq : ((which == 1) ? Wk : Wv);
    const int t = threadIdx.x;
    const int h = t & 63;
    #pragma unroll
    for (int p = 0; p < 16; p++) {
        const int er = (t >> 6) + p * 4;
        ts[er][h] = W[(size_t)(e0 + er) * 64 + h];
    }
    __syncthreads();
    const int ew = t & 63;
    #pragma unroll
    for (int p = 0; p < 16; p++) {
        const int hh = (t >> 6) + p * 4;
        const float f = ts[ew][hh];
        const unsigned short hb = f2bf_rne(f);
        const unsigned short lb = f2bf_rne(f - bf2f(hb));
        const size_t o = (size_t)(which * 64 + hh) * 1024 + e0 + ew;
        wt_hi[o] = hb;
        wt_lo[o] = lb;
    }
}

// ---------------------------------------------------------------------------
// Kernel 1: QKV projection via 32x32x16 MFMA (2x FLOP per fragment byte vs
// 16x16x32 -> block LDS reads halve to 96/step).  Block = 512 thr = 8 waves
// = (tg: 32 tokens) x (eh: 512-wide e-half) x (hh: 96-wide h-half); 64
// tokens/block, 256 blocks.  Stage [192h][32e] hi+lo for both e-halves
// (48 KB) double-buffered; ONE barrier + ONE waitcnt per step: the top-of-s
// barrier proves all waves finished step s-1, so DMA(s+1) into buf (s+1)&1
// is overwrite-safe.  x prefetched one step ahead in regs.
// ---------------------------------------------------------------------------
__global__ __launch_bounds__(512) void proj_kernel(
    const float* __restrict__ x,
    const unsigned short* __restrict__ wt_hi, const unsigned short* __restrict__ wt_lo,
    unsigned short* __restrict__ qhi, unsigned short* __restrict__ qlo,
    unsigned short* __restrict__ khi, unsigned short* __restrict__ klo,
    unsigned short* __restrict__ vt)
{
    __shared__ __align__(16) unsigned char smem[98304];  // 2 x 48KB stage; Red union
    const int tid = threadIdx.x;
    const int w = tid >> 6, lane = tid & 63;
    const int l31 = lane & 31, kh = lane >> 5;     // 32x32 frag: row/col, k-half
    const int tg = w & 1, eh = (w >> 1) & 1, hh = w >> 2;
    const int row0 = (int)blockIdx.x * 64;
    const int tok = row0 + tg * 32 + l31;          // this lane's token (B col)

    f32x16 acc[3];
    #pragma unroll
    for (int mt = 0; mt < 3; mt++)
        #pragma unroll
        for (int r = 0; r < 16; r++) acc[mt][r] = 0.f;

    // lane's x base: k-chunk c reads x[tok][eh*512 + e0 + c*16 + kh*8 .. +8]
    const float* xr = x + (size_t)tok * EE + eh * 512 + kh * 8;

    // DMA lane decomposition: 8 rows x 8 chunks per 1KB group; slot s = chunk s^row
    const int r_l = lane >> 3, sl = lane & 7;
    const int cg = sl ^ r_l;
    const unsigned short* mat = (cg < 4) ? wt_hi : wt_lo;
    const int ce = (cg & 3) * 8;

    auto dma_step = [&](int e0, unsigned char* dstbase) {
        #pragma unroll
        for (int ii = 0; ii < 6; ii++) {
            const int i = w * 6 + ii;              // 0..47
            const int ehc = i / 24;                // e-half region
            const int within = i % 24;             // 8-row group
            const int row = within * 8 + r_l;      // 0..191
            const unsigned short* src = mat + (size_t)row * EE + ehc * 512 + e0 + ce;
            async_copy16(src, dstbase + ehc * 24576 + within * 1024);
        }
    };

    // swizzled read slots (bytes within a 128B stage row), per k-chunk c:
    // hi chunk idx = c*2+kh -> slot (idx ^ (l&7)); lo idx = 4+c*2+kh
    const int r7 = lane & 7;
    const int sh0 = ((0 * 2 + kh) ^ r7) * 16;
    const int sl0 = ((4 + 0 * 2 + kh) ^ r7) * 16;
    const int sh1 = ((1 * 2 + kh) ^ r7) * 16;
    const int sl1 = ((4 + 1 * 2 + kh) ^ r7) * 16;

    // prologue: stage 0 + x(0)
    dma_step(0, smem);
    float4 fc0 = *(const float4*)(xr + 0);
    float4 fc1 = *(const float4*)(xr + 4);
    float4 fc2 = *(const float4*)(xr + 16);
    float4 fc3 = *(const float4*)(xr + 20);
    float4 fn0, fn1, fn2, fn3;

    for (int s = 0; s < 16; s++) {
        wait_vm<0>();                              // own stage-s DMA + x(s) landed
        __builtin_amdgcn_s_barrier();              // stage s valid; all done with s-1
        if (s < 15) {
            const int e1 = (s + 1) * 32;
            dma_step(e1, smem + ((s + 1) & 1) * 49152);
            fn0 = *(const float4*)(xr + e1);
            fn1 = *(const float4*)(xr + e1 + 4);
            fn2 = *(const float4*)(xr + e1 + 16);
            fn3 = *(const float4*)(xr + e1 + 20);
        }

        // convert x -> split-bf16 B-frags (chunk 0 and 1 of this 32-e step)
        float f0[8] = {fc0.x, fc0.y, fc0.z, fc0.w, fc1.x, fc1.y, fc1.z, fc1.w};
        float f1[8] = {fc2.x, fc2.y, fc2.z, fc2.w, fc3.x, fc3.y, fc3.z, fc3.w};
        bf16x8 bh0, bl0, bh1, bl1;
        #pragma unroll
        for (int jj = 0; jj < 8; jj++) {
            unsigned short hb;
            hb = f2bf_rne(f0[jj]); bh0[jj] = (short)hb;
            bl0[jj] = (short)f2bf_rne(f0[jj] - bf2f(hb));
            hb = f2bf_rne(f1[jj]); bh1[jj] = (short)hb;
            bl1[jj] = (short)f2bf_rne(f1[jj] - bf2f(hb));
        }

        const unsigned char* Wbase = smem + (s & 1) * 49152 + eh * 24576;
        #pragma unroll
        for (int mt = 0; mt < 3; mt++) {
            const unsigned char* rb = Wbase + (hh * 96 + mt * 32 + l31) * 128;
            bf16x8 Ah0 = *(const bf16x8*)(rb + sh0);
            bf16x8 Al0 = *(const bf16x8*)(rb + sl0);
            bf16x8 Ah1 = *(const bf16x8*)(rb + sh1);
            bf16x8 Al1 = *(const bf16x8*)(rb + sl1);
            acc[mt] = MFMA32(Ah0, bh0, acc[mt]);
            acc[mt] = MFMA32(Ah0, bl0, acc[mt]);
            acc[mt] = MFMA32(Al0, bh0, acc[mt]);
            acc[mt] = MFMA32(Ah1, bh1, acc[mt]);
            acc[mt] = MFMA32(Ah1, bl1, acc[mt]);
            acc[mt] = MFMA32(Al1, bh1, acc[mt]);
        }
        fc0 = fn0; fc1 = fn1; fc2 = fn2; fc3 = fn3;
    }

    // ---- merge e-halves via Red union ([2 tg][192 h][33 tok] f32 = 50.7 KB) ----
    // C layout (32x32): col = lane&31, row = (reg&3) + 8*(reg>>2) + 4*(lane>>5)
    __syncthreads();                               // all stage reads done before overwrite
    float* Red = (float*)smem;
    if (eh == 1) {
        #pragma unroll
        for (int mt = 0; mt < 3; mt++)
            #pragma unroll
            for (int r = 0; r < 16; r++) {
                const int H = hh * 96 + mt * 32 + (r & 3) + 8 * (r >> 2) + 4 * kh;
                Red[(size_t)(tg * 192 + H) * 33 + l31] = acc[mt][r];
            }
    }
    __syncthreads();
    if (eh == 0) {
        #pragma unroll
        for (int mt = 0; mt < 3; mt++)
            #pragma unroll
            for (int r = 0; r < 16; r++) {
                const int H = hh * 96 + mt * 32 + (r & 3) + 8 * (r >> 2) + 4 * kh;
                acc[mt][r] += Red[(size_t)(tg * 192 + H) * 33 + l31];
            }
        const int bb = tok >> 12, tloc = tok & 4095;
        #pragma unroll
        for (int mt = 0; mt < 3; mt++) {
            #pragma unroll
            for (int gq = 0; gq < 4; gq++) {
                const int Hc = hh * 96 + mt * 32 + gq * 8;   // class (uniform)
                const int H0 = Hc + kh * 4;                  // actual h base
                float fv[4] = {acc[mt][gq * 4 + 0], acc[mt][gq * 4 + 1],
                               acc[mt][gq * 4 + 2], acc[mt][gq * 4 + 3]};
                if (Hc < 64) {                                // q
                    ushort4 hi4, lo4; unsigned short hb;
                    hb = f2bf_rne(fv[0]); hi4.x = hb; lo4.x = f2bf_rne(fv[0] - bf2f(hb));
                    hb = f2bf_rne(fv[1]); hi4.y = hb; lo4.y = f2bf_rne(fv[1] - bf2f(hb));
                    hb = f2bf_rne(fv[2]); hi4.z = hb; lo4.z = f2bf_rne(fv[2] - bf2f(hb));
                    hb = f2bf_rne(fv[3]); hi4.w = hb; lo4.w = f2bf_rne(fv[3] - bf2f(hb));
                    const size_t o = (size_t)tok * 64 + H0;
                    *(ushort4*)(qhi + o) = hi4; *(ushort4*)(qlo + o) = lo4;
                } else if (Hc < 128) {                        // k
                    ushort4 hi4, lo4; unsigned short hb;
                    hb = f2bf_rne(fv[0]); hi4.x = hb; lo4.x = f2bf_rne(fv[0] - bf2f(hb));
                    hb = f2bf_rne(fv[1]); hi4.y = hb; lo4.y = f2bf_rne(fv[1] - bf2f(hb));
                    hb = f2bf_rne(fv[2]); hi4.z = hb; lo4.z = f2bf_rne(fv[2] - bf2f(hb));
                    hb = f2bf_rne(fv[3]); hi4.w = hb; lo4.w = f2bf_rne(fv[3] - bf2f(hb));
                    const size_t o = (size_t)tok * 64 + (H0 - 64);
                    *(ushort4*)(khi + o) = hi4; *(ushort4*)(klo + o) = lo4;
                } else {                                      // v, transposed [h][t]
                    #pragma unroll
                    for (int r = 0; r < 4; r++)
                        vt[((size_t)(bb * 64 + (H0 - 128) + r) << 12) + tloc] =
                            f2bf_rne(fv[r]);
                }
            }
        }
    }
}

// ---------------------------------------------------------------------------
// Kernel 2: flash attention (unchanged from R9): S^T form, static-M softmax,
// uniform blocks — 512-thr block handles pair (gA=bx, gB=127-bx) in two
// sequential split-K-8 phases -> every block runs exactly 129 tiles.
// ---------------------------------------------------------------------------
__global__ __launch_bounds__(512) void flash_kernel(
    const unsigned short* __restrict__ qhi, const unsigned short* __restrict__ qlo,
    const unsigned short* __restrict__ khi, const unsigned short* __restrict__ klo,
    const unsigned short* __restrict__ vt, float* __restrict__ out)
{
    __shared__ __align__(16) unsigned char smem[151552];
    const int tid = threadIdx.x;
    const int w = tid >> 6, lane = tid & 63;
    const int quad = lane >> 4, li = lane & 15;
    const int bx = (int)blockIdx.x;                // 0..63: pair (bx, 127-bx)
    const int b = (int)blockIdx.y;                 // batch
    const float SM = 20.0f;                        // static softmax offset

    const unsigned short* kb_hi = khi + ((size_t)b << 18);
    const unsigned short* kb_lo = klo + ((size_t)b << 18);
    const unsigned short* vtb   = vt  + ((size_t)b << 18) + (size_t)li * 4096 + quad * 8;

    unsigned char* kbase = smem + w * 16384;       // wave-private 2x8KB
    unsigned short* PsA = (unsigned short*)(smem + 131072 + w * 2560);
    unsigned short* PsB = PsA + 640;
    float* Op = (float*)smem;                      // [8][64][33] (phase epilogue)
    float* Ml = (float*)(smem + 67584);            // [8][32]

    const int r_l4 = lane >> 4, s16 = lane & 15;
    const int slh0 = ((quad)      ^ li) * 8;       // K hi, h 0..31
    const int slh1 = ((4 + quad)  ^ li) * 8;       // K hi, h 32..63
    const int sll0 = ((8 + quad)  ^ li) * 8;       // K lo, h 0..31
    const int sll1 = ((12 + quad) ^ li) * 8;       // K lo, h 32..63

    auto dma_tile = [&](int k0, unsigned char* dst) {
        #pragma unroll
        for (int i = 0; i < 8; i++) {
            const int row = i * 4 + r_l4;          // 0..31
            const int c = s16 ^ (row & 15);
            const unsigned short* src = (c < 8)
                ? kb_hi + (size_t)(k0 + row) * 64 + c * 8
                : kb_lo + (size_t)(k0 + row) * 64 + (c - 8) * 8;
            async_copy16(src, dst + i * 1024);
        }
    };

    #pragma unroll 1
    for (int phase = 0; phase < 2; phase++) {
        const int g = phase ? (127 - bx) : bx;
        const int q0 = g * 32;
        const int n_kt = g + 1;                    // 32-token causal K-tiles
        const int tok0 = q0 + li, tok1 = tok0 + 16;

        const size_t qo0 = ((size_t)(b << 12) + tok0) * 64 + quad * 8;
        const size_t qo1 = qo0 + 16 * 64;
        const bf16x8 QhA0 = *(const bf16x8*)(qhi + qo0);
        const bf16x8 QhA1 = *(const bf16x8*)(qhi + qo0 + 32);
        const bf16x8 QlA0 = *(const bf16x8*)(qlo + qo0);
        const bf16x8 QlA1 = *(const bf16x8*)(qlo + qo0 + 32);
        const bf16x8 QhB0 = *(const bf16x8*)(qhi + qo1);
        const bf16x8 QhB1 = *(const bf16x8*)(qhi + qo1 + 32);
        const bf16x8 QlB0 = *(const bf16x8*)(qlo + qo1);
        const bf16x8 QlB1 = *(const bf16x8*)(qlo + qo1 + 32);

        f32x4 accA[4], accB[4];
        #pragma unroll
        for (int mt = 0; mt < 4; mt++) {
            accA[mt] = (f32x4){0.f, 0.f, 0.f, 0.f};
            accB[mt] = (f32x4){0.f, 0.f, 0.f, 0.f};
        }
        float lA = 0.f, lB = 0.f;

        bf16x8 Vc[4], Vn[4];
        int bufp = 0;
        if (w < n_kt) {                            // prologue for tile w
            dma_tile(w * 32, kbase);
            #pragma unroll
            for (int hf = 0; hf < 4; hf++)
                Vc[hf] = *(const bf16x8*)(vtb + (size_t)hf * 65536 + w * 32);
        }

        for (int kt = w; kt < n_kt; kt += 8) {
            const int k0 = kt * 32;

            if (kt + 8 < n_kt) {                   // prefetch next tile
                dma_tile((kt + 8) * 32, kbase + (bufp ^ 1) * 8192);
                #pragma unroll
                for (int hf = 0; hf < 4; hf++)
                    Vn[hf] = *(const bf16x8*)(vtb + (size_t)hf * 65536 + (kt + 8) * 32);
                wait_vm<12>();                     // drain current, keep prefetch
            } else {
                wait_vm<0>();
            }
            const unsigned short* Kw = (const unsigned short*)(kbase + bufp * 8192);

            f32x4 sA[2], sB[2];
            #pragma unroll
            for (int jf = 0; jf < 2; jf++) {
                const unsigned short* rb = Kw + (jf * 16 + li) * 128;  // 256B rows
                bf16x8 Kh0 = *(const bf16x8*)(rb + slh0);
                bf16x8 Kh1 = *(const bf16x8*)(rb + slh1);
                bf16x8 Kl0 = *(const bf16x8*)(rb + sll0);
                bf16x8 Kl1 = *(const bf16x8*)(rb + sll1);
                f32x4 a = (f32x4){0.f, 0.f, 0.f, 0.f};
                a = MFMA16(Kh0, QhA0, a);
                a = MFMA16(Kh1, QhA1, a);
                a = MFMA16(Kh0, QlA0, a);
                a = MFMA16(Kh1, QlA1, a);
                a = MFMA16(Kl0, QhA0, a);
                a = MFMA16(Kl1, QhA1, a);
                sA[jf] = a;
                f32x4 c2 = (f32x4){0.f, 0.f, 0.f, 0.f};
                c2 = MFMA16(Kh0, QhB0, c2);
                c2 = MFMA16(Kh1, QhB1, c2);
                c2 = MFMA16(Kh0, QlB0, c2);
                c2 = MFMA16(Kh1, QlB1, c2);
                c2 = MFMA16(Kl0, QhB0, c2);
                c2 = MFMA16(Kl1, QhB1, c2);
                sB[jf] = c2;
            }

            if (kt == n_kt - 1) {                  // causal mask, diagonal tile
                #pragma unroll
                for (int jf = 0; jf < 2; jf++)
                    #pragma unroll
                    for (int r = 0; r < 4; r++) {
                        const int j = k0 + jf * 16 + quad * 4 + r;
                        if (j > tok0) sA[jf][r] = -1e30f;
                        if (j > tok1) sB[jf][r] = -1e30f;
                    }
            }

            #pragma unroll
            for (int jf = 0; jf < 2; jf++)
                #pragma unroll
                for (int r = 0; r < 4; r++) {
                    sA[jf][r] = __expf(sA[jf][r] - SM); lA += sA[jf][r];
                    sB[jf][r] = __expf(sB[jf][r] - SM); lB += sB[jf][r];
                }

            #pragma unroll
            for (int jf = 0; jf < 2; jf++) {
                ushort4 pa, pb;
                pa.x = f2bf_rne(sA[jf][0]); pa.y = f2bf_rne(sA[jf][1]);
                pa.z = f2bf_rne(sA[jf][2]); pa.w = f2bf_rne(sA[jf][3]);
                pb.x = f2bf_rne(sB[jf][0]); pb.y = f2bf_rne(sB[jf][1]);
                pb.z = f2bf_rne(sB[jf][2]); pb.w = f2bf_rne(sB[jf][3]);
                *(ushort4*)&PsA[li * 40 + jf * 16 + quad * 4] = pa;
                *(ushort4*)&PsB[li * 40 + jf * 16 + quad * 4] = pb;
            }
            const bf16x8 PA = *(const bf16x8*)&PsA[li * 40 + quad * 8];
            const bf16x8 PB = *(const bf16x8*)&PsB[li * 40 + quad * 8];

            #pragma unroll
            for (int hf = 0; hf < 4; hf++) {
                accA[hf] = MFMA16(Vc[hf], PA, accA[hf]);
                accB[hf] = MFMA16(Vc[hf], PB, accB[hf]);
            }
            #pragma unroll
            for (int hf = 0; hf < 4; hf++) Vc[hf] = Vn[hf];
            bufp ^= 1;
        }

        lA += __shfl_xor(lA, 16); lA += __shfl_xor(lA, 32);
        lB += __shfl_xor(lB, 16); lB += __shfl_xor(lB, 32);

        __syncthreads();                           // all waves done with Kbuf
        #pragma unroll
        for (int mt = 0; mt < 4; mt++)
            #pragma unroll
            for (int r = 0; r < 4; r++) {
                Op[(size_t)w * 2112 + (mt * 16 + quad * 4 + r) * 33 + li]      = accA[mt][r];
                Op[(size_t)w * 2112 + (mt * 16 + quad * 4 + r) * 33 + li + 16] = accB[mt][r];
            }
        if (quad == 0) {
            Ml[w * 32 + li]      = lA;
            Ml[w * 32 + 16 + li] = lB;
        }
        __syncthreads();

        const int i  = tid >> 4;                   // 0..31
        const int hc = (tid & 15) * 4;
        float l = 0.f;
        #pragma unroll
        for (int ww = 0; ww < 8; ww++) l += Ml[ww * 32 + i];
        const float inv = 1.0f / (l * 8.0f);       // /= sqrt(64) after softmax
        float4 o = {0.f, 0.f, 0.f, 0.f};
        #pragma unroll
        for (int ww = 0; ww < 8; ww++) {
            const float* base = Op + (size_t)ww * 2112;
            o.x += base[(hc + 0) * 33 + i];
            o.y += base[(hc + 1) * 33 + i];
            o.z += base[(hc + 2) * 33 + i];
            o.w += base[(hc + 3) * 33 + i];
        }
        o.x *= inv; o.y *= inv; o.z *= inv; o.w *= inv;
        *(float4*)(out + ((size_t)(b << 12) + q0 + i) * 64 + hc) = o;
        __syncthreads();                           // Opart free before next phase
    }
}

// ---------------------------------------------------------------------------
extern "C" void kernel_launch(void* const* d_in, const int* in_sizes, int n_in,
                              void* d_out, int out_size, void* d_ws, size_t ws_size,
                              hipStream_t stream)
{
    const float* x  = (const float*)d_in[0];
    const float* Wq = (const float*)d_in[1];
    const float* Wk = (const float*)d_in[2];
    const float* Wv = (const float*)d_in[3];
    float* out = (float*)d_out;

    const size_t n_tok = (size_t)BB * TT * HH;    // 1,048,576
    unsigned short* qhi = (unsigned short*)d_ws;
    unsigned short* qlo = qhi + n_tok;
    unsigned short* khi = qlo + n_tok;
    unsigned short* klo = khi + n_tok;
    unsigned short* vt  = klo + n_tok;            // [B][64][4096]
    unsigned short* wt_hi = vt + n_tok;           // [192][1024]
    unsigned short* wt_lo = wt_hi + 192 * 1024;   // total ~10.75 MB

    wprep_kernel<<<48, 256, 0, stream>>>(Wq, Wk, Wv, wt_hi, wt_lo);
    proj_kernel<<<(BB * TT) / 64, 512, 0, stream>>>(x, wt_hi, wt_lo,
                                                    qhi, qlo, khi, klo, vt);
    flash_kernel<<<dim3(64, BB), 512, 0, stream>>>(qhi, qlo, khi, klo, vt, out);
}